// Round 2
// baseline (511.523 us; speedup 1.0000x reference)
//
#include <hip/hip_runtime.h>
#include <math.h>

#define N_TOK 32768
#define IN_DIM 1024
#define HID 256
#define NE 64

#define PX 68    // Xs pitch (floats): ≡4 mod 32 -> 4-way staging writes, 16B-aligned rows
#define PW 260   // Ws pitch (floats): ≡4 mod 32, 16B-aligned rows
#define PL 65    // logits pitch: ≡1 mod 32 -> conflict-free row scans

// ---------------------------------------------------------------------------
// GEMM1: H[N,256] = relu(X[N,1024] @ W1^T + b1)
// grid 512, 256 threads. Block tile 64 tok x 256 hid. Micro-tile 8x8.
// Wave lane map: tg = lane>>3 (8 token-groups), hg = lane&7 (8 hidden-groups);
// wave w owns hiddens [w*64, w*64+64). => every ds_read_b128 has 8 distinct
// addresses, 2 per 4-bank group (2-way = free), rest broadcast.
// K staged 32 at a time, transposed [k][t]/[k][h], register-prefetch pipeline.
// ---------------------------------------------------------------------------
__global__ __launch_bounds__(256, 2)
void gemm1_relu(const float* __restrict__ x, const float* __restrict__ w1,
                const float* __restrict__ b1, float* __restrict__ h)
{
    __shared__ float Xs[32 * PX];   // 8704 B
    __shared__ float Ws[32 * PW];   // 33280 B

    const int tid  = threadIdx.x;
    const int t0   = blockIdx.x * 64;
    const int wave = tid >> 6;
    const int lane = tid & 63;
    const int tg   = lane >> 3;            // token group 0..7
    const int hg   = lane & 7;             // hidden group 0..7
    const int xoff = tg * 8;               // local token base
    const int woff = wave * 64 + hg * 8;   // local hidden base

    // staging assignment (coalesced global loads)
    const int tx = tid >> 3;               // 0..31
    const int kq = (tid & 7) * 4;          // 0..28

    float acc[8][8];
    #pragma unroll
    for (int i = 0; i < 8; ++i)
        #pragma unroll
        for (int j = 0; j < 8; ++j) acc[i][j] = 0.f;

    // prefetch tile 0 into registers
    float4 xr0, xr1, wr[8];
    {
        xr0 = *(const float4*)(x + (size_t)(t0 + tx) * IN_DIM + kq);
        xr1 = *(const float4*)(x + (size_t)(t0 + tx + 32) * IN_DIM + kq);
        #pragma unroll
        for (int r = 0; r < 8; ++r)
            wr[r] = *(const float4*)(w1 + (size_t)(tx + 32 * r) * IN_DIM + kq);
    }

    for (int kt = 0; kt < 32; ++kt) {
        __syncthreads();   // all waves done reading LDS from previous tile
        {   // write staged registers to transposed LDS
            const float* xp0 = (const float*)&xr0;
            const float* xp1 = (const float*)&xr1;
            #pragma unroll
            for (int j = 0; j < 4; ++j) {
                Xs[(kq + j) * PX + tx]      = xp0[j];
                Xs[(kq + j) * PX + tx + 32] = xp1[j];
            }
            #pragma unroll
            for (int r = 0; r < 8; ++r) {
                const float* wp = (const float*)&wr[r];
                #pragma unroll
                for (int j = 0; j < 4; ++j)
                    Ws[(kq + j) * PW + tx + 32 * r] = wp[j];
            }
        }
        __syncthreads();

        // prefetch next tile (latency hidden behind 2048 FMAs)
        if (kt < 31) {
            const int k0 = (kt + 1) * 32;
            xr0 = *(const float4*)(x + (size_t)(t0 + tx) * IN_DIM + k0 + kq);
            xr1 = *(const float4*)(x + (size_t)(t0 + tx + 32) * IN_DIM + k0 + kq);
            #pragma unroll
            for (int r = 0; r < 8; ++r)
                wr[r] = *(const float4*)(w1 + (size_t)(tx + 32 * r) * IN_DIM + k0 + kq);
        }

        #pragma unroll
        for (int k = 0; k < 32; ++k) {
            float xv[8], wv[8];
            *(float4*)&xv[0] = *(const float4*)&Xs[k * PX + xoff];
            *(float4*)&xv[4] = *(const float4*)&Xs[k * PX + xoff + 4];
            *(float4*)&wv[0] = *(const float4*)&Ws[k * PW + woff];
            *(float4*)&wv[4] = *(const float4*)&Ws[k * PW + woff + 4];
            #pragma unroll
            for (int i = 0; i < 8; ++i)
                #pragma unroll
                for (int j = 0; j < 8; ++j)
                    acc[i][j] = fmaf(xv[i], wv[j], acc[i][j]);
        }
    }

    // epilogue: bias + relu + float4 stores
    float bias[8];
    *(float4*)&bias[0] = *(const float4*)(b1 + woff);
    *(float4*)&bias[4] = *(const float4*)(b1 + woff + 4);
    #pragma unroll
    for (int i = 0; i < 8; ++i) {
        const int t = t0 + xoff + i;
        float4 o0, o1;
        o0.x = fmaxf(acc[i][0] + bias[0], 0.f);
        o0.y = fmaxf(acc[i][1] + bias[1], 0.f);
        o0.z = fmaxf(acc[i][2] + bias[2], 0.f);
        o0.w = fmaxf(acc[i][3] + bias[3], 0.f);
        o1.x = fmaxf(acc[i][4] + bias[4], 0.f);
        o1.y = fmaxf(acc[i][5] + bias[5], 0.f);
        o1.z = fmaxf(acc[i][6] + bias[6], 0.f);
        o1.w = fmaxf(acc[i][7] + bias[7], 0.f);
        *(float4*)(h + (size_t)t * HID + woff)     = o0;
        *(float4*)(h + (size_t)t * HID + woff + 4) = o1;
    }
}

// ---------------------------------------------------------------------------
// GEMM2 + top-2 + softmax. Block tile 64 tok x 64 experts, grid 512.
// Wave lane map: tg4 = lane>>2 (16 token-groups of 4), eg = lane&3; wave w
// owns experts [w*16, w*16+16). Micro-tile 4x4.
// ---------------------------------------------------------------------------
__global__ __launch_bounds__(256, 2)
void gemm2_topk(const float* __restrict__ h, const float* __restrict__ w2,
                const float* __restrict__ b2, float* __restrict__ out)
{
    __shared__ float Hs[32 * PX];    // 8704 B
    __shared__ float W2s[32 * PX];   // 8704 B (64 experts, pitch 68)
    __shared__ float Ls[64 * PL];    // 16640 B

    const int tid  = threadIdx.x;
    const int t0   = blockIdx.x * 64;
    const int wave = tid >> 6;
    const int lane = tid & 63;
    const int tg4  = lane >> 2;            // 0..15 -> tokens tg4*4..+3
    const int eg   = lane & 3;             // expert group
    const int toff = tg4 * 4;
    const int eoff = wave * 16 + eg * 4;

    const int tx = tid >> 3;               // 0..31
    const int kq = (tid & 7) * 4;

    float acc[4][4];
    #pragma unroll
    for (int i = 0; i < 4; ++i)
        #pragma unroll
        for (int j = 0; j < 4; ++j) acc[i][j] = 0.f;

    float4 hr0, hr1, wr0, wr1;
    hr0 = *(const float4*)(h + (size_t)(t0 + tx) * HID + kq);
    hr1 = *(const float4*)(h + (size_t)(t0 + tx + 32) * HID + kq);
    wr0 = *(const float4*)(w2 + (size_t)tx * HID + kq);
    wr1 = *(const float4*)(w2 + (size_t)(tx + 32) * HID + kq);

    for (int kt = 0; kt < 8; ++kt) {
        __syncthreads();
        {
            const float* p0 = (const float*)&hr0;
            const float* p1 = (const float*)&hr1;
            const float* q0 = (const float*)&wr0;
            const float* q1 = (const float*)&wr1;
            #pragma unroll
            for (int j = 0; j < 4; ++j) {
                Hs[(kq + j) * PX + tx]       = p0[j];
                Hs[(kq + j) * PX + tx + 32]  = p1[j];
                W2s[(kq + j) * PX + tx]      = q0[j];
                W2s[(kq + j) * PX + tx + 32] = q1[j];
            }
        }
        __syncthreads();

        if (kt < 7) {
            const int k0 = (kt + 1) * 32;
            hr0 = *(const float4*)(h + (size_t)(t0 + tx) * HID + k0 + kq);
            hr1 = *(const float4*)(h + (size_t)(t0 + tx + 32) * HID + k0 + kq);
            wr0 = *(const float4*)(w2 + (size_t)tx * HID + k0 + kq);
            wr1 = *(const float4*)(w2 + (size_t)(tx + 32) * HID + k0 + kq);
        }

        #pragma unroll
        for (int k = 0; k < 32; ++k) {
            float hv[4], wv[4];
            *(float4*)&hv[0] = *(const float4*)&Hs[k * PX + toff];
            *(float4*)&wv[0] = *(const float4*)&W2s[k * PX + eoff];
            #pragma unroll
            for (int i = 0; i < 4; ++i)
                #pragma unroll
                for (int j = 0; j < 4; ++j)
                    acc[i][j] = fmaf(hv[i], wv[j], acc[i][j]);
        }
    }

    // logits (+bias) -> LDS
    float bb[4];
    *(float4*)&bb[0] = *(const float4*)(b2 + eoff);
    #pragma unroll
    for (int i = 0; i < 4; ++i)
        #pragma unroll
        for (int j = 0; j < 4; ++j)
            Ls[(toff + i) * PL + eoff + j] = acc[i][j] + bb[j];
    __syncthreads();

    // one lane per token: top-2 (strict > keeps lower index on ties, matching
    // jax.lax.top_k), then 2-way softmax.
    if (tid < 64) {
        const int t = tid;
        float m1 = -INFINITY, m2 = -INFINITY;
        int i1 = 0, i2 = 0;
        #pragma unroll 8
        for (int e = 0; e < NE; ++e) {
            float v = Ls[t * PL + e];
            if (v > m1) { m2 = m1; i2 = i1; m1 = v; i1 = e; }
            else if (v > m2) { m2 = v; i2 = e; }
        }
        float e2  = expf(m2 - m1);          // <= 1
        float inv = 1.f / (1.f + e2);
        const int gt = t0 + t;
        out[(size_t)gt * 2 + 0] = (float)i1;
        out[(size_t)gt * 2 + 1] = (float)i2;
        out[(size_t)2 * N_TOK + (size_t)gt * 2 + 0] = inv;
        out[(size_t)2 * N_TOK + (size_t)gt * 2 + 1] = e2 * inv;
    }
}

extern "C" void kernel_launch(void* const* d_in, const int* in_sizes, int n_in,
                              void* d_out, int out_size, void* d_ws, size_t ws_size,
                              hipStream_t stream) {
    const float* x  = (const float*)d_in[0];
    const float* w1 = (const float*)d_in[1];
    const float* b1 = (const float*)d_in[2];
    const float* w2 = (const float*)d_in[3];
    const float* b2 = (const float*)d_in[4];
    float* out = (float*)d_out;
    float* h   = (float*)d_ws;   // 32768*256*4 = 33.6 MB scratch

    gemm1_relu<<<N_TOK / 64, 256, 0, stream>>>(x, w1, b1, h);
    gemm2_topk<<<N_TOK / 64, 256, 0, stream>>>(h, w2, b2, out);
}

// Round 3
// 487.140 us; speedup vs baseline: 1.0501x; 1.0501x over previous
//
#include <hip/hip_runtime.h>
#include <math.h>

#define N_TOK 32768
#define IN_DIM 1024
#define HID 256
#define NE 64

#define PX 68    // Xs pitch (floats): ≡4 mod 32 -> 4-way staging writes, 16B-aligned rows
#define PW 260   // Ws pitch (floats): ≡4 mod 32, 16B-aligned rows
#define PL 65    // logits pitch: ≡1 mod 32 -> conflict-free row scans

// ---------------------------------------------------------------------------
// GEMM1: H[N,256] = relu(X[N,1024] @ W1^T + b1)
// grid 512, 256 threads. Block tile 64 tok x 256 hid. Micro-tile 8x8.
// Wave lane map: tg = lane>>3 (8 token-groups), hg = lane&7 (8 hidden-groups);
// wave w owns hiddens [w*64, w*64+64). => every ds_read_b128 has 8 distinct
// addresses, 2 per 4-bank group (2-way = free), rest broadcast.
// K staged 32 at a time, transposed [k][t]/[k][h], register-prefetch pipeline.
// __launch_bounds__(256,1): grid is 2 blocks/CU anyway; capping at 128 VGPRs
// (256,2) made the prefetch registers SPILL (round-2: WRITE_SIZE 290 MB).
// ---------------------------------------------------------------------------
__global__ __launch_bounds__(256, 1)
void gemm1_relu(const float* __restrict__ x, const float* __restrict__ w1,
                const float* __restrict__ b1, float* __restrict__ h)
{
    __shared__ float Xs[32 * PX];   // 8704 B
    __shared__ float Ws[32 * PW];   // 33280 B

    const int tid  = threadIdx.x;
    const int t0   = blockIdx.x * 64;
    const int wave = tid >> 6;
    const int lane = tid & 63;
    const int tg   = lane >> 3;            // token group 0..7
    const int hg   = lane & 7;             // hidden group 0..7
    const int xoff = tg * 8;               // local token base
    const int woff = wave * 64 + hg * 8;   // local hidden base

    // staging assignment (coalesced global loads)
    const int tx = tid >> 3;               // 0..31
    const int kq = (tid & 7) * 4;          // 0..28

    float acc[8][8];
    #pragma unroll
    for (int i = 0; i < 8; ++i)
        #pragma unroll
        for (int j = 0; j < 8; ++j) acc[i][j] = 0.f;

    // prefetch tile 0 into registers
    float4 xr0, xr1, wr[8];
    {
        xr0 = *(const float4*)(x + (size_t)(t0 + tx) * IN_DIM + kq);
        xr1 = *(const float4*)(x + (size_t)(t0 + tx + 32) * IN_DIM + kq);
        #pragma unroll
        for (int r = 0; r < 8; ++r)
            wr[r] = *(const float4*)(w1 + (size_t)(tx + 32 * r) * IN_DIM + kq);
    }

    for (int kt = 0; kt < 32; ++kt) {
        __syncthreads();   // all waves done reading LDS from previous tile
        {   // write staged registers to transposed LDS
            const float* xp0 = (const float*)&xr0;
            const float* xp1 = (const float*)&xr1;
            #pragma unroll
            for (int j = 0; j < 4; ++j) {
                Xs[(kq + j) * PX + tx]      = xp0[j];
                Xs[(kq + j) * PX + tx + 32] = xp1[j];
            }
            #pragma unroll
            for (int r = 0; r < 8; ++r) {
                const float* wp = (const float*)&wr[r];
                #pragma unroll
                for (int j = 0; j < 4; ++j)
                    Ws[(kq + j) * PW + tx + 32 * r] = wp[j];
            }
        }
        __syncthreads();

        // prefetch next tile (latency hidden behind 2048 FMAs)
        if (kt < 31) {
            const int k0 = (kt + 1) * 32;
            xr0 = *(const float4*)(x + (size_t)(t0 + tx) * IN_DIM + k0 + kq);
            xr1 = *(const float4*)(x + (size_t)(t0 + tx + 32) * IN_DIM + k0 + kq);
            #pragma unroll
            for (int r = 0; r < 8; ++r)
                wr[r] = *(const float4*)(w1 + (size_t)(tx + 32 * r) * IN_DIM + k0 + kq);
        }

        #pragma unroll
        for (int k = 0; k < 32; ++k) {
            float xv[8], wv[8];
            *(float4*)&xv[0] = *(const float4*)&Xs[k * PX + xoff];
            *(float4*)&xv[4] = *(const float4*)&Xs[k * PX + xoff + 4];
            *(float4*)&wv[0] = *(const float4*)&Ws[k * PW + woff];
            *(float4*)&wv[4] = *(const float4*)&Ws[k * PW + woff + 4];
            #pragma unroll
            for (int i = 0; i < 8; ++i)
                #pragma unroll
                for (int j = 0; j < 8; ++j)
                    acc[i][j] = fmaf(xv[i], wv[j], acc[i][j]);
        }
    }

    // epilogue: bias + relu + float4 stores
    float bias[8];
    *(float4*)&bias[0] = *(const float4*)(b1 + woff);
    *(float4*)&bias[4] = *(const float4*)(b1 + woff + 4);
    #pragma unroll
    for (int i = 0; i < 8; ++i) {
        const int t = t0 + xoff + i;
        float4 o0, o1;
        o0.x = fmaxf(acc[i][0] + bias[0], 0.f);
        o0.y = fmaxf(acc[i][1] + bias[1], 0.f);
        o0.z = fmaxf(acc[i][2] + bias[2], 0.f);
        o0.w = fmaxf(acc[i][3] + bias[3], 0.f);
        o1.x = fmaxf(acc[i][4] + bias[4], 0.f);
        o1.y = fmaxf(acc[i][5] + bias[5], 0.f);
        o1.z = fmaxf(acc[i][6] + bias[6], 0.f);
        o1.w = fmaxf(acc[i][7] + bias[7], 0.f);
        *(float4*)(h + (size_t)t * HID + woff)     = o0;
        *(float4*)(h + (size_t)t * HID + woff + 4) = o1;
    }
}

// ---------------------------------------------------------------------------
// GEMM2 + top-2 + softmax. Block tile 64 tok x 64 experts, grid 512.
// Wave lane map: tg4 = lane>>2 (16 token-groups of 4), eg = lane&3; wave w
// owns experts [w*16, w*16+16). Micro-tile 4x4.
// ---------------------------------------------------------------------------
__global__ __launch_bounds__(256, 2)
void gemm2_topk(const float* __restrict__ h, const float* __restrict__ w2,
                const float* __restrict__ b2, float* __restrict__ out)
{
    __shared__ float Hs[32 * PX];    // 8704 B
    __shared__ float W2s[32 * PX];   // 8704 B (64 experts, pitch 68)
    __shared__ float Ls[64 * PL];    // 16640 B

    const int tid  = threadIdx.x;
    const int t0   = blockIdx.x * 64;
    const int wave = tid >> 6;
    const int lane = tid & 63;
    const int tg4  = lane >> 2;            // 0..15 -> tokens tg4*4..+3
    const int eg   = lane & 3;             // expert group
    const int toff = tg4 * 4;
    const int eoff = wave * 16 + eg * 4;

    const int tx = tid >> 3;               // 0..31
    const int kq = (tid & 7) * 4;

    float acc[4][4];
    #pragma unroll
    for (int i = 0; i < 4; ++i)
        #pragma unroll
        for (int j = 0; j < 4; ++j) acc[i][j] = 0.f;

    float4 hr0, hr1, wr0, wr1;
    hr0 = *(const float4*)(h + (size_t)(t0 + tx) * HID + kq);
    hr1 = *(const float4*)(h + (size_t)(t0 + tx + 32) * HID + kq);
    wr0 = *(const float4*)(w2 + (size_t)tx * HID + kq);
    wr1 = *(const float4*)(w2 + (size_t)(tx + 32) * HID + kq);

    for (int kt = 0; kt < 8; ++kt) {
        __syncthreads();
        {
            const float* p0 = (const float*)&hr0;
            const float* p1 = (const float*)&hr1;
            const float* q0 = (const float*)&wr0;
            const float* q1 = (const float*)&wr1;
            #pragma unroll
            for (int j = 0; j < 4; ++j) {
                Hs[(kq + j) * PX + tx]       = p0[j];
                Hs[(kq + j) * PX + tx + 32]  = p1[j];
                W2s[(kq + j) * PX + tx]      = q0[j];
                W2s[(kq + j) * PX + tx + 32] = q1[j];
            }
        }
        __syncthreads();

        if (kt < 7) {
            const int k0 = (kt + 1) * 32;
            hr0 = *(const float4*)(h + (size_t)(t0 + tx) * HID + k0 + kq);
            hr1 = *(const float4*)(h + (size_t)(t0 + tx + 32) * HID + k0 + kq);
            wr0 = *(const float4*)(w2 + (size_t)tx * HID + k0 + kq);
            wr1 = *(const float4*)(w2 + (size_t)(tx + 32) * HID + k0 + kq);
        }

        #pragma unroll
        for (int k = 0; k < 32; ++k) {
            float hv[4], wv[4];
            *(float4*)&hv[0] = *(const float4*)&Hs[k * PX + toff];
            *(float4*)&wv[0] = *(const float4*)&W2s[k * PX + eoff];
            #pragma unroll
            for (int i = 0; i < 4; ++i)
                #pragma unroll
                for (int j = 0; j < 4; ++j)
                    acc[i][j] = fmaf(hv[i], wv[j], acc[i][j]);
        }
    }

    // logits (+bias) -> LDS
    float bb[4];
    *(float4*)&bb[0] = *(const float4*)(b2 + eoff);
    #pragma unroll
    for (int i = 0; i < 4; ++i)
        #pragma unroll
        for (int j = 0; j < 4; ++j)
            Ls[(toff + i) * PL + eoff + j] = acc[i][j] + bb[j];
    __syncthreads();

    // one lane per token: top-2 (strict > keeps lower index on ties, matching
    // jax.lax.top_k), then 2-way softmax.
    if (tid < 64) {
        const int t = tid;
        float m1 = -INFINITY, m2 = -INFINITY;
        int i1 = 0, i2 = 0;
        #pragma unroll 8
        for (int e = 0; e < NE; ++e) {
            float v = Ls[t * PL + e];
            if (v > m1) { m2 = m1; i2 = i1; m1 = v; i1 = e; }
            else if (v > m2) { m2 = v; i2 = e; }
        }
        float e2  = expf(m2 - m1);          // <= 1
        float inv = 1.f / (1.f + e2);
        const int gt = t0 + t;
        out[(size_t)gt * 2 + 0] = (float)i1;
        out[(size_t)gt * 2 + 1] = (float)i2;
        out[(size_t)2 * N_TOK + (size_t)gt * 2 + 0] = inv;
        out[(size_t)2 * N_TOK + (size_t)gt * 2 + 1] = e2 * inv;
    }
}

extern "C" void kernel_launch(void* const* d_in, const int* in_sizes, int n_in,
                              void* d_out, int out_size, void* d_ws, size_t ws_size,
                              hipStream_t stream) {
    const float* x  = (const float*)d_in[0];
    const float* w1 = (const float*)d_in[1];
    const float* b1 = (const float*)d_in[2];
    const float* w2 = (const float*)d_in[3];
    const float* b2 = (const float*)d_in[4];
    float* out = (float*)d_out;
    float* h   = (float*)d_ws;   // 32768*256*4 = 33.6 MB scratch

    gemm1_relu<<<N_TOK / 64, 256, 0, stream>>>(x, w1, b1, h);
    gemm2_topk<<<N_TOK / 64, 256, 0, stream>>>(h, w2, b2, out);
}

// Round 4
// 471.976 us; speedup vs baseline: 1.0838x; 1.0321x over previous
//
#include <hip/hip_runtime.h>
#include <math.h>

#define N_TOK 32768
#define IN_DIM 1024
#define HID 256
#define NE 64
#define MT 8      // tokens per wave
#define KU 4      // k unroll per half-chunk (ping-pong: 2*KU per loop trip)

// d_ws layout (floats):
//   w1t [IN_DIM][HID]  at 0        (262144)
//   w2t [HID][NE]      at 262144   (16384)
//   h   [N_TOK][HID]   at 278528   (8388608)   total ~34.7 MB

// ---------------------------------------------------------------------------
// One-time transposes: w1[256][1024] -> w1t[1024][256]; w2[64][256] -> w2t[256][64]
// ---------------------------------------------------------------------------
__global__ void prep_transpose(const float* __restrict__ w1, const float* __restrict__ w2,
                               float* __restrict__ w1t, float* __restrict__ w2t)
{
    __shared__ float t[32][33];
    const int b = blockIdx.x;
    const float* src; float* dst; int R, C, bx, by;
    if (b < 256) { src = w1; dst = w1t; R = HID; C = IN_DIM; bx = (b & 31) * 32; by = (b >> 5) * 32; }
    else { int bb = b - 256; src = w2; dst = w2t; R = NE; C = HID; bx = (bb & 7) * 32; by = (bb >> 3) * 32; }
    const int lx = threadIdx.x & 31, ly = threadIdx.x >> 5;
    #pragma unroll
    for (int j = 0; j < 4; ++j)
        t[ly + 8 * j][lx] = src[(size_t)(by + ly + 8 * j) * C + bx + lx];
    __syncthreads();
    #pragma unroll
    for (int j = 0; j < 4; ++j)
        dst[(size_t)(bx + ly + 8 * j) * R + by + lx] = t[lx][ly + 8 * j];
}

// ---------------------------------------------------------------------------
// GEMM1: H = relu(X @ W1T + b1). No LDS, no barriers.
// Wave = 8 tokens x 256 hiddens. lane -> hiddens [4*lane, 4*lane+4).
// X is wave-uniform -> scalar (SGPR) loads; W1T k-major -> coalesced dwordx4
// from L2. Ping-pong register double-buffer over k (chunks of KU=4, 2/trip).
// ---------------------------------------------------------------------------
__global__ __launch_bounds__(256)
void gemm1_relu(const float* __restrict__ x, const float* __restrict__ w1t,
                const float* __restrict__ b1, float* __restrict__ h)
{
    const int lane = threadIdx.x & 63;
    const int wv   = __builtin_amdgcn_readfirstlane(threadIdx.x >> 6);
    const int tb   = blockIdx.x * (4 * MT) + wv * MT;     // uniform
    const float* xb = x + (size_t)tb * IN_DIM;            // uniform base -> s_load
    const float* wb = w1t + lane * 4;

    float acc[MT][4];
    #pragma unroll
    for (int i = 0; i < MT; ++i)
        #pragma unroll
        for (int j = 0; j < 4; ++j) acc[i][j] = 0.f;

    float4 xA[MT], xB[MT], wA[KU], wB[KU];
    #pragma unroll
    for (int i = 0; i < MT; ++i) xA[i] = *(const float4*)(xb + i * IN_DIM);
    #pragma unroll
    for (int u = 0; u < KU; ++u) wA[u] = *(const float4*)(wb + u * HID);

    for (int k0 = 0; k0 < IN_DIM; k0 += 2 * KU) {
        const int kb = k0 + KU;                           // always < IN_DIM
        #pragma unroll
        for (int i = 0; i < MT; ++i) xB[i] = *(const float4*)(xb + i * IN_DIM + kb);
        #pragma unroll
        for (int u = 0; u < KU; ++u) wB[u] = *(const float4*)(wb + (size_t)(kb + u) * HID);

        #pragma unroll
        for (int u = 0; u < KU; ++u)
            #pragma unroll
            for (int i = 0; i < MT; ++i) {
                const float xs = ((const float*)&xA[i])[u];
                acc[i][0] = fmaf(xs, wA[u].x, acc[i][0]);
                acc[i][1] = fmaf(xs, wA[u].y, acc[i][1]);
                acc[i][2] = fmaf(xs, wA[u].z, acc[i][2]);
                acc[i][3] = fmaf(xs, wA[u].w, acc[i][3]);
            }

        int ka = k0 + 2 * KU; ka = (ka < IN_DIM) ? ka : 0;   // last trip: dummy reload
        #pragma unroll
        for (int i = 0; i < MT; ++i) xA[i] = *(const float4*)(xb + i * IN_DIM + ka);
        #pragma unroll
        for (int u = 0; u < KU; ++u) wA[u] = *(const float4*)(wb + (size_t)(ka + u) * HID);

        #pragma unroll
        for (int u = 0; u < KU; ++u)
            #pragma unroll
            for (int i = 0; i < MT; ++i) {
                const float xs = ((const float*)&xB[i])[u];
                acc[i][0] = fmaf(xs, wB[u].x, acc[i][0]);
                acc[i][1] = fmaf(xs, wB[u].y, acc[i][1]);
                acc[i][2] = fmaf(xs, wB[u].z, acc[i][2]);
                acc[i][3] = fmaf(xs, wB[u].w, acc[i][3]);
            }
    }

    const float4 bv = *(const float4*)(b1 + lane * 4);
    #pragma unroll
    for (int i = 0; i < MT; ++i) {
        float4 o;
        o.x = fmaxf(acc[i][0] + bv.x, 0.f);
        o.y = fmaxf(acc[i][1] + bv.y, 0.f);
        o.z = fmaxf(acc[i][2] + bv.z, 0.f);
        o.w = fmaxf(acc[i][3] + bv.w, 0.f);
        *(float4*)(h + (size_t)(tb + i) * HID + lane * 4) = o;
    }
}

// ---------------------------------------------------------------------------
// GEMM2 + top-2 + softmax. Wave = 8 tokens x 64 experts; lane -> expert.
// H rows wave-uniform -> scalar loads; W2T[k][lane] coalesced dword.
// Logits -> per-wave LDS slab (no barrier: same-wave write->read), lanes 0..7
// each scan one token row (strict > keeps lower index on ties = jax.lax.top_k).
// ---------------------------------------------------------------------------
__global__ __launch_bounds__(256)
void gemm2_topk(const float* __restrict__ h, const float* __restrict__ w2t,
                const float* __restrict__ b2, float* __restrict__ out)
{
    __shared__ float Ls[4][MT][NE + 1];   // 8320 B, per-wave slabs

    const int lane = threadIdx.x & 63;
    const int wv   = __builtin_amdgcn_readfirstlane(threadIdx.x >> 6);
    const int tb   = blockIdx.x * (4 * MT) + wv * MT;
    const float* hb = h + (size_t)tb * HID;              // uniform -> s_load
    const float* wb = w2t + lane;

    float acc[MT];
    #pragma unroll
    for (int i = 0; i < MT; ++i) acc[i] = 0.f;

    float4 xA[MT], xB[MT];
    float  wA[KU], wB[KU];
    #pragma unroll
    for (int i = 0; i < MT; ++i) xA[i] = *(const float4*)(hb + i * HID);
    #pragma unroll
    for (int u = 0; u < KU; ++u) wA[u] = wb[(size_t)u * NE];

    for (int k0 = 0; k0 < HID; k0 += 2 * KU) {
        const int kb = k0 + KU;
        #pragma unroll
        for (int i = 0; i < MT; ++i) xB[i] = *(const float4*)(hb + i * HID + kb);
        #pragma unroll
        for (int u = 0; u < KU; ++u) wB[u] = wb[(size_t)(kb + u) * NE];

        #pragma unroll
        for (int u = 0; u < KU; ++u)
            #pragma unroll
            for (int i = 0; i < MT; ++i)
                acc[i] = fmaf(((const float*)&xA[i])[u], wA[u], acc[i]);

        int ka = k0 + 2 * KU; ka = (ka < HID) ? ka : 0;
        #pragma unroll
        for (int i = 0; i < MT; ++i) xA[i] = *(const float4*)(hb + i * HID + ka);
        #pragma unroll
        for (int u = 0; u < KU; ++u) wA[u] = wb[(size_t)(ka + u) * NE];

        #pragma unroll
        for (int u = 0; u < KU; ++u)
            #pragma unroll
            for (int i = 0; i < MT; ++i)
                acc[i] = fmaf(((const float*)&xB[i])[u], wB[u], acc[i]);
    }

    const float bb = b2[lane];
    #pragma unroll
    for (int i = 0; i < MT; ++i)
        Ls[wv][i][lane] = acc[i] + bb;
    // same-wave LDS write->read: compiler inserts lgkmcnt wait; no barrier needed.

    if (lane < MT) {
        const int t = lane;
        float m1 = -INFINITY, m2 = -INFINITY;
        int i1 = 0, i2 = 0;
        #pragma unroll 8
        for (int e = 0; e < NE; ++e) {
            float v = Ls[wv][t][e];
            if (v > m1) { m2 = m1; i2 = i1; m1 = v; i1 = e; }
            else if (v > m2) { m2 = v; i2 = e; }
        }
        float e2  = expf(m2 - m1);          // <= 1
        float inv = 1.f / (1.f + e2);
        const int gt = tb + t;
        out[(size_t)gt * 2 + 0] = (float)i1;
        out[(size_t)gt * 2 + 1] = (float)i2;
        out[(size_t)2 * N_TOK + (size_t)gt * 2 + 0] = inv;
        out[(size_t)2 * N_TOK + (size_t)gt * 2 + 1] = e2 * inv;
    }
}

extern "C" void kernel_launch(void* const* d_in, const int* in_sizes, int n_in,
                              void* d_out, int out_size, void* d_ws, size_t ws_size,
                              hipStream_t stream) {
    const float* x  = (const float*)d_in[0];
    const float* w1 = (const float*)d_in[1];
    const float* b1 = (const float*)d_in[2];
    const float* w2 = (const float*)d_in[3];
    const float* b2 = (const float*)d_in[4];
    float* out = (float*)d_out;

    float* w1t = (float*)d_ws;                 // 262144 floats
    float* w2t = w1t + (size_t)IN_DIM * HID;   // 16384 floats
    float* h   = w2t + (size_t)HID * NE;       // 8388608 floats

    prep_transpose<<<272, 256, 0, stream>>>(w1, w2, w1t, w2t);
    gemm1_relu<<<N_TOK / (4 * MT), 256, 0, stream>>>(x, w1t, b1, h);
    gemm2_topk<<<N_TOK / (4 * MT), 256, 0, stream>>>(h, w2t, b2, out);
}

// Round 5
// 467.458 us; speedup vs baseline: 1.0943x; 1.0097x over previous
//
#include <hip/hip_runtime.h>
#include <math.h>

#define N_TOK 32768
#define IN_DIM 1024
#define HID 256
#define NE 64
#define MT 8        // tokens per wave
#define KU 4        // k per half-chunk (ping-pong)
#define TB 32       // tokens per block
#define KHALF 512   // K per wave (intra-block split-K x2)
#define PH 260      // H LDS pitch (floats), =0 mod 4 for float4
#define PL 68       // logits LDS pitch

// d_ws: w1t [1024][256] at 0 (262144 floats); w2t [256][64] next (16384).

// ---------------------------------------------------------------------------
// One-time transposes: w1[256][1024]->w1t[1024][256]; w2[64][256]->w2t[256][64]
// ---------------------------------------------------------------------------
__global__ void prep_transpose(const float* __restrict__ w1, const float* __restrict__ w2,
                               float* __restrict__ w1t, float* __restrict__ w2t)
{
    __shared__ float t[32][33];
    const int b = blockIdx.x;
    const float* src; float* dst; int R, C, bx, by;
    if (b < 256) { src = w1; dst = w1t; R = HID; C = IN_DIM; bx = (b & 31) * 32; by = (b >> 5) * 32; }
    else { int bb = b - 256; src = w2; dst = w2t; R = NE; C = HID; bx = (bb & 7) * 32; by = (bb >> 3) * 32; }
    const int lx = threadIdx.x & 31, ly = threadIdx.x >> 5;
    #pragma unroll
    for (int j = 0; j < 4; ++j)
        t[ly + 8 * j][lx] = src[(size_t)(by + ly + 8 * j) * C + bx + lx];
    __syncthreads();
    #pragma unroll
    for (int j = 0; j < 4; ++j)
        dst[(size_t)(bx + ly + 8 * j) * R + by + lx] = t[lx][ly + 8 * j];
}

// ---------------------------------------------------------------------------
// Fused: H=relu(X@W1T+b1) [intra-block split-K x2] -> logits=H@W2T+b2 ->
// top-2 -> softmax. 512 thr = 8 waves; waves 0-3: K[0,512), 4-7: K[512,1024),
// same 32 tokens. X wave-uniform -> s_load; W1T k-major -> coalesced dwordx4.
// Partials meet in LDS; H never goes to HBM.
// __launch_bounds__(512,8): 8 waves/EU => VGPR cap 64 (main loop needs ~36).
// ---------------------------------------------------------------------------
__global__ __launch_bounds__(512, 8)
void gating_fused(const float* __restrict__ x, const float* __restrict__ w1t,
                  const float* __restrict__ b1, const float* __restrict__ w2t,
                  const float* __restrict__ b2, float* __restrict__ out)
{
    __shared__ float Hs[2 * TB * PH];   // 66560 B: per-K-half partial H [t][k]
    __shared__ float Ls2[TB * PL];      // 8704 B: logits [t][e]
    __shared__ float b1s[HID];          // 1024 B
    __shared__ float b2s[NE];           // 256 B

    const int tid  = threadIdx.x;
    const int lane = tid & 63;
    const int wave = __builtin_amdgcn_readfirstlane(tid >> 6);  // 0..7, uniform
    const int half = wave >> 2;                                 // K half
    const int wv4  = wave & 3;                                  // token group
    const int tloc = wv4 * MT;
    const int tb   = blockIdx.x * TB + tloc;
    const int kbase = half * KHALF;

    if (tid < HID) b1s[tid] = b1[tid];
    if (tid < NE)  b2s[tid] = b2[tid];

    const float* xb = x + (size_t)tb * IN_DIM + kbase;          // uniform -> s_load
    const float* wb = w1t + (size_t)kbase * HID + lane * 4;

    float acc[MT][4];
    #pragma unroll
    for (int i = 0; i < MT; ++i)
        #pragma unroll
        for (int j = 0; j < 4; ++j) acc[i][j] = 0.f;

    float4 xA[MT], xB[MT], wA[KU], wB[KU];
    #pragma unroll
    for (int i = 0; i < MT; ++i) xA[i] = *(const float4*)(xb + i * IN_DIM);
    #pragma unroll
    for (int u = 0; u < KU; ++u) wA[u] = *(const float4*)(wb + (size_t)u * HID);

    for (int k0 = 0; k0 < KHALF; k0 += 2 * KU) {
        const int kb = k0 + KU;
        #pragma unroll
        for (int i = 0; i < MT; ++i) xB[i] = *(const float4*)(xb + i * IN_DIM + kb);
        #pragma unroll
        for (int u = 0; u < KU; ++u) wB[u] = *(const float4*)(wb + (size_t)(kb + u) * HID);

        #pragma unroll
        for (int u = 0; u < KU; ++u)
            #pragma unroll
            for (int i = 0; i < MT; ++i) {
                const float xs = ((const float*)&xA[i])[u];
                acc[i][0] = fmaf(xs, wA[u].x, acc[i][0]);
                acc[i][1] = fmaf(xs, wA[u].y, acc[i][1]);
                acc[i][2] = fmaf(xs, wA[u].z, acc[i][2]);
                acc[i][3] = fmaf(xs, wA[u].w, acc[i][3]);
            }

        int ka = k0 + 2 * KU; ka = (ka < KHALF) ? ka : 0;       // last trip: dummy
        #pragma unroll
        for (int i = 0; i < MT; ++i) xA[i] = *(const float4*)(xb + i * IN_DIM + ka);
        #pragma unroll
        for (int u = 0; u < KU; ++u) wA[u] = *(const float4*)(wb + (size_t)(ka + u) * HID);

        #pragma unroll
        for (int u = 0; u < KU; ++u)
            #pragma unroll
            for (int i = 0; i < MT; ++i) {
                const float xs = ((const float*)&xB[i])[u];
                acc[i][0] = fmaf(xs, wB[u].x, acc[i][0]);
                acc[i][1] = fmaf(xs, wB[u].y, acc[i][1]);
                acc[i][2] = fmaf(xs, wB[u].z, acc[i][2]);
                acc[i][3] = fmaf(xs, wB[u].w, acc[i][3]);
            }
    }

    // partial H -> LDS (this wave's K-half slab)
    {
        float* hsl = Hs + half * (TB * PH);
        #pragma unroll
        for (int i = 0; i < MT; ++i)
            *(float4*)(hsl + (tloc + i) * PH + 4 * lane) = *(float4*)&acc[i][0];
    }
    __syncthreads();

    // finalize H in place: Hs0 = relu(Hs0 + Hs1 + b1). 8192 entries / 512 thr.
    #pragma unroll
    for (int r = 0; r < 16; ++r) {
        const int idx = tid + 512 * r;
        const int t = idx >> 8, k = idx & 255;
        const int a = t * PH + k;
        Hs[a] = fmaxf(Hs[a] + Hs[TB * PH + a] + b1s[k], 0.f);
    }
    __syncthreads();

    // gemm2 in-block: thread -> (token = tid>>4, experts 4eg..4eg+3)
    {
        const int t  = tid >> 4;
        const int eg = tid & 15;
        const float* wq = w2t + 4 * eg;
        float a2[4] = {0.f, 0.f, 0.f, 0.f};
        #pragma unroll 4
        for (int k = 0; k < HID; ++k) {
            const float hv = Hs[t * PH + k];                    // broadcast-ish
            const float4 w4 = *(const float4*)(wq + (size_t)k * NE);  // L1-hot
            a2[0] = fmaf(hv, w4.x, a2[0]);
            a2[1] = fmaf(hv, w4.y, a2[1]);
            a2[2] = fmaf(hv, w4.z, a2[2]);
            a2[3] = fmaf(hv, w4.w, a2[3]);
        }
        float4 o;
        o.x = a2[0] + b2s[4 * eg + 0];
        o.y = a2[1] + b2s[4 * eg + 1];
        o.z = a2[2] + b2s[4 * eg + 2];
        o.w = a2[3] + b2s[4 * eg + 3];
        *(float4*)(Ls2 + t * PL + 4 * eg) = o;
    }
    __syncthreads();

    // top-2 + softmax, one thread per token. Strict > keeps lower index on
    // ties == jax.lax.top_k. out[0..2N)=indices(float), out[2N..4N)=gates.
    if (tid < TB) {
        const int t = tid;
        float m1 = -INFINITY, m2 = -INFINITY;
        int i1 = 0, i2 = 0;
        #pragma unroll 8
        for (int e = 0; e < NE; ++e) {
            float v = Ls2[t * PL + e];
            if (v > m1) { m2 = m1; i2 = i1; m1 = v; i1 = e; }
            else if (v > m2) { m2 = v; i2 = e; }
        }
        float e2  = expf(m2 - m1);      // <= 1
        float inv = 1.f / (1.f + e2);
        const int gt = blockIdx.x * TB + t;
        out[(size_t)gt * 2 + 0] = (float)i1;
        out[(size_t)gt * 2 + 1] = (float)i2;
        out[(size_t)2 * N_TOK + (size_t)gt * 2 + 0] = inv;
        out[(size_t)2 * N_TOK + (size_t)gt * 2 + 1] = e2 * inv;
    }
}

extern "C" void kernel_launch(void* const* d_in, const int* in_sizes, int n_in,
                              void* d_out, int out_size, void* d_ws, size_t ws_size,
                              hipStream_t stream) {
    const float* x  = (const float*)d_in[0];
    const float* w1 = (const float*)d_in[1];
    const float* b1 = (const float*)d_in[2];
    const float* w2 = (const float*)d_in[3];
    const float* b2 = (const float*)d_in[4];
    float* out = (float*)d_out;

    float* w1t = (float*)d_ws;                 // 262144 floats
    float* w2t = w1t + (size_t)IN_DIM * HID;   // 16384 floats

    prep_transpose<<<272, 256, 0, stream>>>(w1, w2, w1t, w2t);
    gating_fused<<<N_TOK / TB, 512, 0, stream>>>(x, w1t, b1, w2t, b2, out);
}